// Round 6
// baseline (680.350 us; speedup 1.0000x reference)
//
#include <hip/hip_runtime.h>
#include <math.h>

typedef unsigned short u16;
typedef unsigned int u32;
typedef __attribute__((ext_vector_type(8))) short short8;   // 8 bf16 (4 VGPRs)
typedef __attribute__((ext_vector_type(4))) float f32x4;

__device__ __forceinline__ float bf2f(u16 u) {
  union { u32 i; float f; } v; v.i = ((u32)u) << 16; return v.f;
}
__device__ __forceinline__ u16 f2bf(float f) {
  union { float f; u32 i; } v; v.f = f;
  u32 i = v.i;
  i += 0x7fffu + ((i >> 16) & 1u);   // round-to-nearest-even
  return (u16)(i >> 16);
}

// dtype-polymorphic loads (F32: inputs are float32; else bf16 bits)
template<bool F32>
__device__ __forceinline__ float ld(const void* p, int i) {
  if (F32) return ((const float*)p)[i];
  return bf2f(((const u16*)p)[i]);
}

// ---------------------------------------------------------------------------
// Kernel 0: detect input dtype (fp32 vs bf16-packed).
// ---------------------------------------------------------------------------
__global__ __launch_bounds__(64)
void detect_kernel(const void* __restrict__ xv, int* __restrict__ flag) {
  const u32* xw = (const u32*)xv;
  const int t = threadIdx.x;
  int bad = 0;
  for (int i = t; i < 1024; i += 64) {
    const int e = (int)((xw[i] >> 7) & 0xFF);
    if (e < 90 || e > 150) bad++;
  }
#pragma unroll
  for (int m = 1; m < 64; m <<= 1) bad += __shfl_xor(bad, m);
  if (t == 0) *flag = (bad > 256) ? 1 : 0;
}

// ---------------------------------------------------------------------------
// Token-major shifted gather: lane (s, cg) loads token s's channels cg*8..+7
// of window (wbase + w) as two 16B loads (8 lanes cover a 256B row).
// ---------------------------------------------------------------------------
template<bool F32>
__device__ __forceinline__ void gather8(const void* __restrict__ x, int chunk,
                                        int w, int s, int cg, float* pf) {
  const int b     = chunk >> 13;
  const int wbase = (chunk & 8191) << 2;
  const int widx  = wbase + w;
  const int wz = widx >> 10, wy = (widx >> 5) & 31, wx = widx & 31;
  const int od = (2*wz + ((s>>2)&1) + 1) & 63;
  const int oh = (2*wy + ((s>>1)&1) + 1) & 63;
  const int ow = (2*wx + ( s    &1) + 1) & 63;
  const int base = (((b<<18) + ((od<<12)|(oh<<6)|ow)) << 6) + cg*8;
  if (F32) {
    const f32x4 a = *(const f32x4*)((const float*)x + base);
    const f32x4 c = *(const f32x4*)((const float*)x + base + 4);
    pf[0]=a[0]; pf[1]=a[1]; pf[2]=a[2]; pf[3]=a[3];
    pf[4]=c[0]; pf[5]=c[1]; pf[6]=c[2]; pf[7]=c[3];
  } else {
    const short8 a = *(const short8*)((const u16*)x + base);
#pragma unroll
    for (int j = 0; j < 8; ++j) pf[j] = bf2f((u16)a[j]);
  }
}

// bug-faithful window-reverse scatter base for token tok of chunk's windows
__device__ __forceinline__ int scat(int chunk, int tok) {
  const int b     = chunk >> 13;
  const int wbase = (chunk & 8191) << 2;
  const int widx = wbase + (tok >> 3);
  const int s    = tok & 7;
  const int wz = widx >> 10, wy = (widx >> 5) & 31, wx = widx & 31;
  const int fd = (2*wz + ((wy>>3)&1) + 1) & 63;
  const int Hb = 8*(wy&7) + 4*(wx>>4) + (wy>>4);
  const int Wb = 4*(wx&15);
  const int i = (s>>2)&1, j = (s>>1)&1, k = s&1;
  const int fh = (Hb + 2*j + 1) & 63;
  const int fw = (Wb + 2*i + k + 1) & 63;
  return ((b<<18) + ((fd<<12)|(fh<<6)|fw)) << 6;
}

template<bool F32>
__device__ __forceinline__ void loadx8(const void* __restrict__ x, int base,
                                       float* xr) {
  if (F32) {
    const f32x4 a = *(const f32x4*)((const float*)x + base);
    const f32x4 c = *(const f32x4*)((const float*)x + base + 4);
    xr[0]=a[0]; xr[1]=a[1]; xr[2]=a[2]; xr[3]=a[3];
    xr[4]=c[0]; xr[5]=c[1]; xr[6]=c[2]; xr[7]=c[3];
  } else {
    const short8 a = *(const short8*)((const u16*)x + base);
#pragma unroll
    for (int j = 0; j < 8; ++j) xr[j] = bf2f((u16)a[j]);
  }
}

// ---------------------------------------------------------------------------
// Fused kernel: LN1 + window-attn + proj + residual + LN2 + MLP + residual.
// Block 256 thr (4 waves), chunk = 4 windows = 32 tokens, 16384 chunks,
// persistent grid 2048. ALL weight fragments register-resident (~96 VGPR;
// round-3 showed streamed weights thrash L2). y never touches global:
// LN2+MLP are row-local, so they run on window-ordered rows and the final
// store scatters once. One scat per lane per chunk (token-major epilogue).
//
// LDS pool (u16 units, 40800 B total):
//   aL   [0,2304)      32x72 bf16: LN1 out, later LN2 out
//   qkvL [2304,9216)   q/k/v (3x 32x72); overlaid by hL [2304,10752) 32x264
//   yL   @10752        f32 32x68: y = x + attn + pb
//   xL   @15104        f32 32x68: residual x; reused as oL (mlp out)
//   pL   @19456        f32: [0..255] n1g,n1b,n2g,n2b; [256..472) rpb
// 8 barriers/chunk. Gather + residual loads software-pipelined across chunks.
// ---------------------------------------------------------------------------
#define MFMA __builtin_amdgcn_mfma_f32_16x16x32_bf16

template<bool F32>
__device__ __forceinline__ void fused_body(
    const void* __restrict__ x,
    const void* __restrict__ n1g, const void* __restrict__ n1b,
    const void* __restrict__ qkvw, const void* __restrict__ qkvb,
    const void* __restrict__ rpb,
    const void* __restrict__ projw, const void* __restrict__ projb,
    const void* __restrict__ n2g, const void* __restrict__ n2b,
    const void* __restrict__ mw1, const void* __restrict__ mb1,
    const void* __restrict__ mw2, const void* __restrict__ mb2,
    float* __restrict__ out, u16* __restrict__ P)
{
  u16* aL   = P;                     // 32x72
  u16* qL   = P + 2304;
  u16* kL   = P + 4608;
  u16* vL   = P + 6912;
  u16* hL   = P + 2304;              // overlay (q/k/v dead when hL live)
  float* yL = (float*)(P + 10752);   // 32x68
  float* xL = (float*)(P + 15104);   // 32x68 (later oL)
  float* oL = xL;
  float* pL = (float*)(P + 19456);   // 256 LN params
  float* rpL = pL + 256;             // 216 rpb values

  const int tid  = threadIdx.x;
  const int w    = tid >> 6, l = tid & 63;
  const int quad = l >> 4,  col = l & 15;
  const int s8   = l >> 3,  cg  = l & 7;   // token-major (also head/query)
  const int tok_l = w*8 + s8;

  // ---- stage LN params + rpb into LDS ----
  {
    const int a = tid >> 6, c = tid & 63;
    const void* src = (a==0) ? n1g : (a==1) ? n1b : (a==2) ? n2g : n2b;
    pL[tid] = ld<F32>(src, c);
    if (tid < 216) rpL[tid] = ld<F32>(rpb, tid);
  }

  // ---- register-resident weight fragments (once per block) ----
  short8 bq[3][2];                 // qkv cols w*48 + nt*16 + col
#pragma unroll
  for (int nt = 0; nt < 3; ++nt)
#pragma unroll
    for (int kt = 0; kt < 2; ++kt) {
      short8 f;
#pragma unroll
      for (int j = 0; j < 8; ++j)
        f[j] = (short)f2bf(ld<F32>(qkvw, (kt*32 + quad*8 + j)*192 + w*48 + nt*16 + col));
      bq[nt][kt] = f;
    }
  float qb[3];
#pragma unroll
  for (int nt = 0; nt < 3; ++nt) qb[nt] = ld<F32>(qkvb, w*48 + nt*16 + col);
  short8 bp[2];                    // proj cols w*16 + col
#pragma unroll
  for (int kt = 0; kt < 2; ++kt) {
    short8 f;
#pragma unroll
    for (int j = 0; j < 8; ++j)
      f[j] = (short)f2bf(ld<F32>(projw, (kt*32 + quad*8 + j)*64 + w*16 + col));
    bp[kt] = f;
  }
  const float pbv = ld<F32>(projb, w*16 + col);
  short8 b1f[2][4];                // W1 cols w*64 + nt*16 + col
#pragma unroll
  for (int kt = 0; kt < 2; ++kt)
#pragma unroll
    for (int nt = 0; nt < 4; ++nt) {
      short8 f;
#pragma unroll
      for (int j = 0; j < 8; ++j)
        f[j] = (short)f2bf(ld<F32>(mw1, (kt*32 + quad*8 + j)*256 + w*64 + nt*16 + col));
      b1f[kt][nt] = f;
    }
  short8 b2f[8];                   // W2 col w*16 + col
#pragma unroll
  for (int kt = 0; kt < 8; ++kt) {
    short8 f;
#pragma unroll
    for (int j = 0; j < 8; ++j)
      f[j] = (short)f2bf(ld<F32>(mw2, (kt*32 + quad*8 + j)*64 + w*16 + col));
    b2f[kt] = f;
  }
  float b1v[4];
#pragma unroll
  for (int nt = 0; nt < 4; ++nt) b1v[nt] = ld<F32>(mb1, w*64 + nt*16 + col);
  const float b2v = ld<F32>(mb2, w*16 + col);

  const int rel = 3 * (((s8>>1)&1) - ((cg>>1)&1) + 1)
                +     (((s8>>2)&1) - ((cg>>2)&1) + 1)
                +     (( s8    &1) - ( cg    &1) + 1);

  __syncthreads();   // pL/rpL ready

  const int G = gridDim.x;
  // prologue prefetch (gather + residual) for first chunk
  float pf[8], xr[8];
  int off_c = scat(blockIdx.x, tok_l) + cg*8;
  gather8<F32>(x, blockIdx.x, w, s8, cg, pf);
  loadx8<F32>(x, off_c, xr);

  for (int chunk = blockIdx.x; chunk < 16384; chunk += G) {
    const int wbase = (chunk & 8191) << 2;
    const int widx0 = wbase + w;
    const int wz0 = widx0 >> 10, wy0 = (widx0 >> 5) & 31, wx0 = widx0 & 31;

    // ---- P0: LN1 (token-major 3-stage reduce) + stash residual x ----
    {
      float s1 = 0.f, sq = 0.f;
#pragma unroll
      for (int j = 0; j < 8; ++j) { s1 += pf[j]; sq += pf[j]*pf[j]; }
#pragma unroll
      for (int m = 1; m < 8; m <<= 1) {
        s1 += __shfl_xor(s1, m);
        sq += __shfl_xor(sq, m);
      }
      const float mu  = s1 * 0.015625f;
      const float var = sq * 0.015625f - mu * mu;
      const float rs  = rsqrtf(var + 1e-5f);
      short8 av;
#pragma unroll
      for (int j = 0; j < 8; ++j)
        av[j] = (short)f2bf((pf[j] - mu) * rs * pL[cg*8 + j] + pL[64 + cg*8 + j]);
      *(short8*)&aL[tok_l*72 + cg*8] = av;
      *(f32x4*)&xL[tok_l*68 + cg*8]     = (f32x4){xr[0], xr[1], xr[2], xr[3]};
      *(f32x4*)&xL[tok_l*68 + cg*8 + 4] = (f32x4){xr[4], xr[5], xr[6], xr[7]};
    }
    int off_n = off_c;
    if (chunk + G < 16384) {           // cross-chunk prefetch
      gather8<F32>(x, chunk + G, w, s8, cg, pf);
      off_n = scat(chunk + G, tok_l) + cg*8;
      loadx8<F32>(x, off_n, xr);
    }
    __syncthreads();                                       // B1: aL/xL ready

    // ---- P1: QKV MFMA, A[32x64] @ wave's 64x48 slab -> q/k/v LDS ----
    {
      short8 aF[2][2];
#pragma unroll
      for (int mt = 0; mt < 2; ++mt)
#pragma unroll
        for (int kt = 0; kt < 2; ++kt)
          aF[mt][kt] = *(const short8*)&aL[(mt*16 + col)*72 + kt*32 + quad*8];
#pragma unroll
      for (int nt = 0; nt < 3; ++nt) {
        f32x4 a0 = (f32x4){0.f,0.f,0.f,0.f}, a1 = (f32x4){0.f,0.f,0.f,0.f};
        a0 = MFMA(aF[0][0], bq[nt][0], a0, 0, 0, 0);
        a0 = MFMA(aF[0][1], bq[nt][1], a0, 0, 0, 0);
        a1 = MFMA(aF[1][0], bq[nt][0], a1, 0, 0, 0);
        a1 = MFMA(aF[1][1], bq[nt][1], a1, 0, 0, 0);
        const int nb  = w*48 + nt*16;
        u16* dst      = (nb < 64) ? qL : (nb < 128) ? kL : vL;
        const int chb = (nb & 63) + col;
        const float scl = (nb < 64) ? 0.35355339059327373f : 1.0f;
        const float bb  = qb[nt];
#pragma unroll
        for (int r = 0; r < 4; ++r) {
          dst[(quad*4 + r)*72 + chb]      = f2bf((a0[r] + bb) * scl);
          dst[(16 + quad*4 + r)*72 + chb] = f2bf((a1[r] + bb) * scl);
        }
      }
    }
    __syncthreads();                                       // B2: q/k/v ready

    // ---- P2: softmax for window w (lane = (head s8, query cg)) ----
    {
      const int tq = w*8 + cg;
      float qr[8];
      {
        const short8 qv = *(const short8*)&qL[tq*72 + s8*8];
#pragma unroll
        for (int d = 0; d < 8; ++d) qr[d] = bf2f((u16)qv[d]);
      }
      float sc8[8];
#pragma unroll
      for (int kk = 0; kk < 8; ++kk) {
        const short8 kv = *(const short8*)&kL[(w*8 + kk)*72 + s8*8];
        float a = 0.f;
#pragma unroll
        for (int d = 0; d < 8; ++d) a += qr[d] * bf2f((u16)kv[d]);
        sc8[kk] = a + rpL[rel*8 + kk];
      }
      {
        int cnts[8];
#pragma unroll
        for (int p = 0; p < 8; ++p) {
          const int sd = 2*wz0 + ((p>>2)&1);
          const int sh = 2*wy0 + ((p>>1)&1);
          const int sw = 2*wx0 + (p&1);
          cnts[p] = (sd >= 62 ? sd - 61 : 0)*9 + (sh >= 62 ? sh - 61 : 0)*3
                  + (sw >= 62 ? sw - 61 : 0);
        }
#pragma unroll
        for (int kk = 0; kk < 8; ++kk)
          if (cnts[kk] != cnts[cg]) sc8[kk] -= 100.f;
      }
      float mx = sc8[0];
#pragma unroll
      for (int kk = 1; kk < 8; ++kk) mx = fmaxf(mx, sc8[kk]);
      float pr[8], lsum = 0.f;
#pragma unroll
      for (int kk = 0; kk < 8; ++kk) { pr[kk] = __expf(sc8[kk] - mx); lsum += pr[kk]; }
      const float inv = __builtin_amdgcn_rcpf(lsum);
      float o[8];
#pragma unroll
      for (int d = 0; d < 8; ++d) o[d] = 0.f;
#pragma unroll
      for (int kk = 0; kk < 8; ++kk) {
        const short8 vv = *(const short8*)&vL[(w*8 + kk)*72 + s8*8];
#pragma unroll
        for (int d = 0; d < 8; ++d) o[d] += pr[kk] * bf2f((u16)vv[d]);
      }
      short8 ov;
#pragma unroll
      for (int d = 0; d < 8; ++d) ov[d] = (short)f2bf(o[d] * inv);
      *(short8*)&qL[tq*72 + s8*8] = ov;    // O into own q-slot (lane-private)
    }
    __syncthreads();                                       // B3: O ready

    // ---- P3: proj MFMA + y = x + attn + pb -> yL (fp32) ----
    {
      f32x4 c0 = (f32x4){0.f,0.f,0.f,0.f}, c1 = (f32x4){0.f,0.f,0.f,0.f};
      c0 = MFMA(*(const short8*)&qL[(col)*72 + quad*8],         bp[0], c0, 0, 0, 0);
      c0 = MFMA(*(const short8*)&qL[(col)*72 + 32 + quad*8],    bp[1], c0, 0, 0, 0);
      c1 = MFMA(*(const short8*)&qL[(16+col)*72 + quad*8],      bp[0], c1, 0, 0, 0);
      c1 = MFMA(*(const short8*)&qL[(16+col)*72 + 32 + quad*8], bp[1], c1, 0, 0, 0);
#pragma unroll
      for (int r = 0; r < 4; ++r) {
        const int r0 = quad*4 + r, r1 = 16 + quad*4 + r;
        yL[r0*68 + w*16 + col] = xL[r0*68 + w*16 + col] + c0[r] + pbv;
        yL[r1*68 + w*16 + col] = xL[r1*68 + w*16 + col] + c1[r] + pbv;
      }
    }
    __syncthreads();                                       // B4: yL ready

    // ---- P4: LN2 (token-major) -> aL (reused) ----
    {
      float yv[8];
      const f32x4 a = *(const f32x4*)&yL[tok_l*68 + cg*8];
      const f32x4 c = *(const f32x4*)&yL[tok_l*68 + cg*8 + 4];
      yv[0]=a[0]; yv[1]=a[1]; yv[2]=a[2]; yv[3]=a[3];
      yv[4]=c[0]; yv[5]=c[1]; yv[6]=c[2]; yv[7]=c[3];
      float s1 = 0.f, sq = 0.f;
#pragma unroll
      for (int j = 0; j < 8; ++j) { s1 += yv[j]; sq += yv[j]*yv[j]; }
#pragma unroll
      for (int m = 1; m < 8; m <<= 1) {
        s1 += __shfl_xor(s1, m);
        sq += __shfl_xor(sq, m);
      }
      const float mu  = s1 * 0.015625f;
      const float var = sq * 0.015625f - mu * mu;
      const float rs  = rsqrtf(var + 1e-5f);
      short8 av;
#pragma unroll
      for (int j = 0; j < 8; ++j)
        av[j] = (short)f2bf((yv[j] - mu) * rs * pL[128 + cg*8 + j] + pL[192 + cg*8 + j]);
      *(short8*)&aL[tok_l*72 + cg*8] = av;
    }
    __syncthreads();                                       // B5: aL2 ready

    // ---- P5: MLP GEMM1 + tanh-GELU -> hL (overlays q/k/v) ----
    {
      short8 aF[2][2];
#pragma unroll
      for (int mt = 0; mt < 2; ++mt)
#pragma unroll
        for (int kt = 0; kt < 2; ++kt)
          aF[mt][kt] = *(const short8*)&aL[(mt*16 + col)*72 + kt*32 + quad*8];
#pragma unroll
      for (int nt = 0; nt < 4; ++nt) {
        f32x4 m0 = (f32x4){0.f,0.f,0.f,0.f}, m1 = (f32x4){0.f,0.f,0.f,0.f};
        m0 = MFMA(aF[0][0], b1f[0][nt], m0, 0, 0, 0);
        m0 = MFMA(aF[0][1], b1f[1][nt], m0, 0, 0, 0);
        m1 = MFMA(aF[1][0], b1f[0][nt], m1, 0, 0, 0);
        m1 = MFMA(aF[1][1], b1f[1][nt], m1, 0, 0, 0);
        const float bb = b1v[nt];
#pragma unroll
        for (int r = 0; r < 4; ++r) {
          {
            const float h = m0[r] + bb;
            const float u = h * (1.5957691216f + 0.0713548162f * (h * h));
            const float e = __expf(u);
            hL[(quad*4 + r)*264 + w*64 + nt*16 + col] =
                f2bf(h - h * __builtin_amdgcn_rcpf(e + 1.f));
          }
          {
            const float h = m1[r] + bb;
            const float u = h * (1.5957691216f + 0.0713548162f * (h * h));
            const float e = __expf(u);
            hL[(16 + quad*4 + r)*264 + w*64 + nt*16 + col] =
                f2bf(h - h * __builtin_amdgcn_rcpf(e + 1.f));
          }
        }
      }
    }
    __syncthreads();                                       // B6: hL ready

    // ---- P6: MLP GEMM2 -> oL (reuses xL region; xL dead since P3) ----
    {
      f32x4 o0 = (f32x4){0.f,0.f,0.f,0.f}, o1 = (f32x4){0.f,0.f,0.f,0.f};
#pragma unroll
      for (int kt = 0; kt < 8; ++kt) {
        o0 = MFMA(*(const short8*)&hL[(col)*264 + kt*32 + quad*8],    b2f[kt], o0, 0, 0, 0);
        o1 = MFMA(*(const short8*)&hL[(16+col)*264 + kt*32 + quad*8], b2f[kt], o1, 0, 0, 0);
      }
#pragma unroll
      for (int r = 0; r < 4; ++r) {
        const int r0 = quad*4 + r, r1 = 16 + quad*4 + r;
        oL[r0*68 + w*16 + col] = o0[r] + b2v;
        oL[r1*68 + w*16 + col] = o1[r] + b2v;
      }
    }
    __syncthreads();                                       // B7: oL ready

    // ---- P7: final token-major scattered store: out = y + mlp ----
    {
      const f32x4 ya = *(const f32x4*)&yL[tok_l*68 + cg*8];
      const f32x4 yb = *(const f32x4*)&yL[tok_l*68 + cg*8 + 4];
      const f32x4 oa = *(const f32x4*)&oL[tok_l*68 + cg*8];
      const f32x4 ob = *(const f32x4*)&oL[tok_l*68 + cg*8 + 4];
      f32x4 sa, sb;
#pragma unroll
      for (int j = 0; j < 4; ++j) { sa[j] = ya[j] + oa[j]; sb[j] = yb[j] + ob[j]; }
      *(f32x4*)&out[off_c]     = sa;
      *(f32x4*)&out[off_c + 4] = sb;
    }
    __syncthreads();   // B8: protect aL/xL/yL/oL before next chunk's writes
    off_c = off_n;
  }
}

__global__ __launch_bounds__(256, 3)
void fused_kernel(const void* __restrict__ x,
                  const void* __restrict__ n1g, const void* __restrict__ n1b,
                  const void* __restrict__ qkvw, const void* __restrict__ qkvb,
                  const void* __restrict__ rpb,
                  const void* __restrict__ projw, const void* __restrict__ projb,
                  const void* __restrict__ n2g, const void* __restrict__ n2b,
                  const void* __restrict__ mw1, const void* __restrict__ mb1,
                  const void* __restrict__ mw2, const void* __restrict__ mb2,
                  const int* __restrict__ flag, float* __restrict__ out)
{
  __shared__ __align__(16) u16 P[20400];   // 40,800 B pool (see fused_body)
  if (*flag)
    fused_body<true >(x, n1g, n1b, qkvw, qkvb, rpb, projw, projb,
                      n2g, n2b, mw1, mb1, mw2, mb2, out, P);
  else
    fused_body<false>(x, n1g, n1b, qkvw, qkvb, rpb, projw, projb,
                      n2g, n2b, mw1, mb1, mw2, mb2, out, P);
}

extern "C" void kernel_launch(void* const* d_in, const int* in_sizes, int n_in,
                              void* d_out, int out_size, void* d_ws, size_t ws_size,
                              hipStream_t stream) {
  const void* x     = d_in[0];
  const void* n1g   = d_in[1];
  const void* n1b   = d_in[2];
  const void* qkvw  = d_in[3];
  const void* qkvb  = d_in[4];
  const void* rpb   = d_in[5];
  const void* projw = d_in[6];
  const void* projb = d_in[7];
  const void* n2g   = d_in[8];
  const void* n2b   = d_in[9];
  const void* mw1   = d_in[10];
  const void* mb1   = d_in[11];
  const void* mw2   = d_in[12];
  const void* mb2   = d_in[13];
  float* out = (float*)d_out;
  int* flag  = (int*)d_ws;

  detect_kernel<<<dim3(1), dim3(64), 0, stream>>>(x, flag);
  fused_kernel<<<dim3(2048), dim3(256), 0, stream>>>(
      x, n1g, n1b, qkvw, qkvb, rpb, projw, projb,
      n2g, n2b, mw1, mb1, mw2, mb2, flag, out);
}

// Round 7
// 460.084 us; speedup vs baseline: 1.4788x; 1.4788x over previous
//
#include <hip/hip_runtime.h>
#include <math.h>

typedef unsigned short u16;
typedef unsigned int u32;
typedef __attribute__((ext_vector_type(8))) short short8;   // 8 bf16 (4 VGPRs)
typedef __attribute__((ext_vector_type(4))) float f32x4;

__device__ __forceinline__ float bf2f(u16 u) {
  union { u32 i; float f; } v; v.i = ((u32)u) << 16; return v.f;
}
__device__ __forceinline__ u16 f2bf(float f) {
  union { float f; u32 i; } v; v.f = f;
  u32 i = v.i;
  i += 0x7fffu + ((i >> 16) & 1u);   // round-to-nearest-even
  return (u16)(i >> 16);
}

// dtype-polymorphic loads (F32: inputs are float32; else bf16 bits)
template<bool F32>
__device__ __forceinline__ float ld(const void* p, int i) {
  if (F32) return ((const float*)p)[i];
  return bf2f(((const u16*)p)[i]);
}

// ---------------------------------------------------------------------------
// Kernel 0: detect input dtype (fp32 vs bf16-packed).
// ---------------------------------------------------------------------------
__global__ __launch_bounds__(64)
void detect_kernel(const void* __restrict__ xv, int* __restrict__ flag) {
  const u32* xw = (const u32*)xv;
  const int t = threadIdx.x;
  int bad = 0;
  for (int i = t; i < 1024; i += 64) {
    const int e = (int)((xw[i] >> 7) & 0xFF);
    if (e < 90 || e > 150) bad++;
  }
#pragma unroll
  for (int m = 1; m < 64; m <<= 1) bad += __shfl_xor(bad, m);
  if (t == 0) *flag = (bad > 256) ? 1 : 0;
}

// ---------------------------------------------------------------------------
// Token-major shifted gather: lane (s, cg) loads token s's channels cg*8..+7
// of window (wbase + w) as two 16B loads (8 lanes cover a 256B row).
// ---------------------------------------------------------------------------
template<bool F32>
__device__ __forceinline__ void gather8(const void* __restrict__ x, int chunk,
                                        int w, int s, int cg, float* pf) {
  const int b     = chunk >> 13;
  const int wbase = (chunk & 8191) << 2;
  const int widx  = wbase + w;
  const int wz = widx >> 10, wy = (widx >> 5) & 31, wx = widx & 31;
  const int od = (2*wz + ((s>>2)&1) + 1) & 63;
  const int oh = (2*wy + ((s>>1)&1) + 1) & 63;
  const int ow = (2*wx + ( s    &1) + 1) & 63;
  const int base = (((b<<18) + ((od<<12)|(oh<<6)|ow)) << 6) + cg*8;
  if (F32) {
    const f32x4 a = *(const f32x4*)((const float*)x + base);
    const f32x4 c = *(const f32x4*)((const float*)x + base + 4);
    pf[0]=a[0]; pf[1]=a[1]; pf[2]=a[2]; pf[3]=a[3];
    pf[4]=c[0]; pf[5]=c[1]; pf[6]=c[2]; pf[7]=c[3];
  } else {
    const short8 a = *(const short8*)((const u16*)x + base);
#pragma unroll
    for (int j = 0; j < 8; ++j) pf[j] = bf2f((u16)a[j]);
  }
}

// bug-faithful window-reverse scatter base for token tok of chunk's windows
__device__ __forceinline__ int scat(int chunk, int tok) {
  const int b     = chunk >> 13;
  const int wbase = (chunk & 8191) << 2;
  const int widx = wbase + (tok >> 3);
  const int s    = tok & 7;
  const int wz = widx >> 10, wy = (widx >> 5) & 31, wx = widx & 31;
  const int fd = (2*wz + ((wy>>3)&1) + 1) & 63;
  const int Hb = 8*(wy&7) + 4*(wx>>4) + (wy>>4);
  const int Wb = 4*(wx&15);
  const int i = (s>>2)&1, j = (s>>1)&1, k = s&1;
  const int fh = (Hb + 2*j + 1) & 63;
  const int fw = (Wb + 2*i + k + 1) & 63;
  return ((b<<18) + ((fd<<12)|(fh<<6)|fw)) << 6;
}

// ---------------------------------------------------------------------------
// Kernel 1: LN1 + shifted-window attention + proj + residual -> out (y, fp32).
// Block 256 thr (4 waves), chunk = 4 windows = 32 tokens, persistent grid 2048.
// Weight fragments register-resident. q/k/v kept in LDS as f32 (saves the
// f2bf pack + bf2f unpack VALU in the softmax phase); O packed bf16 into aL
// (dead after the QKV MFMA, fenced by B2). Mask applied only for boundary
// windows (wz/wy/wx == 31) -- wave-uniform branch, exact.
// ---------------------------------------------------------------------------
#define MFMA __builtin_amdgcn_mfma_f32_16x16x32_bf16

template<bool F32>
__device__ __forceinline__ void attn_body(
    const void* __restrict__ x,
    const void* __restrict__ n1g, const void* __restrict__ n1b,
    const void* __restrict__ qkvw, const void* __restrict__ qkvb,
    const void* __restrict__ rpb,
    const void* __restrict__ projw, const void* __restrict__ projb,
    float* __restrict__ out,
    u16* __restrict__ aL, float* __restrict__ qF,
    float* __restrict__ kF, float* __restrict__ vF)
{
  const int tid  = threadIdx.x;
  const int w    = tid >> 6, l = tid & 63;
  const int quad = l >> 4,  col = l & 15;
  const int s8   = l >> 3,  cg  = l & 7;   // token-major split (= head, query)

  // LN1 per-channel params for this lane's 8 channels
  float g1v[8], be1v[8];
#pragma unroll
  for (int j = 0; j < 8; ++j) {
    g1v[j]  = ld<F32>(n1g, cg*8 + j);
    be1v[j] = ld<F32>(n1b, cg*8 + j);
  }

  // ---- register-resident weight fragments (once per block) ----
  short8 bq[3][2];                 // qkv cols w*48 + nt*16 + col, [nt][kt]
#pragma unroll
  for (int nt = 0; nt < 3; ++nt)
#pragma unroll
    for (int kt = 0; kt < 2; ++kt) {
      short8 f;
#pragma unroll
      for (int j = 0; j < 8; ++j)
        f[j] = (short)f2bf(ld<F32>(qkvw, (kt*32 + quad*8 + j)*192 + w*48 + nt*16 + col));
      bq[nt][kt] = f;
    }
  float qb[3];
#pragma unroll
  for (int nt = 0; nt < 3; ++nt) qb[nt] = ld<F32>(qkvb, w*48 + nt*16 + col);
  short8 bp[2];                    // proj cols w*16 + col, [kt]
#pragma unroll
  for (int kt = 0; kt < 2; ++kt) {
    short8 f;
#pragma unroll
    for (int j = 0; j < 8; ++j)
      f[j] = (short)f2bf(ld<F32>(projw, (kt*32 + quad*8 + j)*64 + w*16 + col));
    bp[kt] = f;
  }
  const float pbv = ld<F32>(projb, w*16 + col);
  const int rel = 3 * (((s8>>1)&1) - ((cg>>1)&1) + 1)
                +     (((s8>>2)&1) - ((cg>>2)&1) + 1)
                +     (( s8    &1) - ( cg    &1) + 1);
  float rpv[8];
#pragma unroll
  for (int kk = 0; kk < 8; ++kk) rpv[kk] = ld<F32>(rpb, rel*8 + kk);

  float pf[8];
  gather8<F32>(x, blockIdx.x, w, s8, cg, pf);   // prologue prefetch

  for (int chunk = blockIdx.x; chunk < 16384; chunk += 2048) {
    const int wbase = (chunk & 8191) << 2;
    const int widx0 = wbase + w;
    const int wz0 = widx0 >> 10, wy0 = (widx0 >> 5) & 31, wx0 = widx0 & 31;

    // ---- phase 1: LN1, token-major 3-stage group reduce ----
    {
      float s1 = 0.f, sq = 0.f;
#pragma unroll
      for (int j = 0; j < 8; ++j) { s1 += pf[j]; sq += pf[j]*pf[j]; }
#pragma unroll
      for (int m = 1; m < 8; m <<= 1) {
        s1 += __shfl_xor(s1, m);
        sq += __shfl_xor(sq, m);
      }
      const float mu  = s1 * 0.015625f;
      const float var = sq * 0.015625f - mu * mu;
      const float rs  = rsqrtf(var + 1e-5f);
      short8 av;
#pragma unroll
      for (int j = 0; j < 8; ++j)
        av[j] = (short)f2bf((pf[j] - mu) * rs * g1v[j] + be1v[j]);
      *(short8*)&aL[(w*8 + s8)*72 + cg*8] = av;
    }
    if (chunk + 2048 < 16384) gather8<F32>(x, chunk + 2048, w, s8, cg, pf);
    __syncthreads();                                       // B1: aL ready

    // ---- phase 2: QKV MFMA, A[32x64] @ wave's 64x48 slab -> q/k/v (f32) ----
    {
      short8 aF[2][2];
#pragma unroll
      for (int mt = 0; mt < 2; ++mt)
#pragma unroll
        for (int kt = 0; kt < 2; ++kt)
          aF[mt][kt] = *(const short8*)&aL[(mt*16 + col)*72 + kt*32 + quad*8];
#pragma unroll
      for (int nt = 0; nt < 3; ++nt) {
        f32x4 a0 = (f32x4){0.f,0.f,0.f,0.f}, a1 = (f32x4){0.f,0.f,0.f,0.f};
        a0 = MFMA(aF[0][0], bq[nt][0], a0, 0, 0, 0);
        a0 = MFMA(aF[0][1], bq[nt][1], a0, 0, 0, 0);
        a1 = MFMA(aF[1][0], bq[nt][0], a1, 0, 0, 0);
        a1 = MFMA(aF[1][1], bq[nt][1], a1, 0, 0, 0);
        const int nb  = w*48 + nt*16;                 // global qkv col base
        float* dst    = (nb < 64) ? qF : (nb < 128) ? kF : vF;
        const int chb = (nb & 63) + col;
        const float scl = (nb < 64) ? 0.35355339059327373f : 1.0f;
        const float bb  = qb[nt];
#pragma unroll
        for (int r = 0; r < 4; ++r) {
          dst[(quad*4 + r)*68 + chb]      = (a0[r] + bb) * scl;
          dst[(16 + quad*4 + r)*68 + chb] = (a1[r] + bb) * scl;
        }
      }
    }
    __syncthreads();                                       // B2: q/k/v ready

    // ---- phase 3: softmax for window w (lane = (head s8, query cg)) ----
    {
      const int tq = w*8 + cg;
      float qr[8];
      {
        const f32x4 qa = *(const f32x4*)&qF[tq*68 + s8*8];
        const f32x4 qc = *(const f32x4*)&qF[tq*68 + s8*8 + 4];
        qr[0]=qa[0]; qr[1]=qa[1]; qr[2]=qa[2]; qr[3]=qa[3];
        qr[4]=qc[0]; qr[5]=qc[1]; qr[6]=qc[2]; qr[7]=qc[3];
      }
      float sc8[8];
#pragma unroll
      for (int kk = 0; kk < 8; ++kk) {
        const f32x4 ka = *(const f32x4*)&kF[(w*8 + kk)*68 + s8*8];
        const f32x4 kc = *(const f32x4*)&kF[(w*8 + kk)*68 + s8*8 + 4];
        float a = qr[0]*ka[0] + qr[1]*ka[1] + qr[2]*ka[2] + qr[3]*ka[3]
                + qr[4]*kc[0] + qr[5]*kc[1] + qr[6]*kc[2] + qr[7]*kc[3];
        sc8[kk] = a + rpv[kk];
      }
      // shift-mask: nonzero only for boundary windows (exact; wave-uniform)
      if ((wz0 == 31) || (wy0 == 31) || (wx0 == 31)) {
        int cnts[8];
#pragma unroll
        for (int p = 0; p < 8; ++p) {
          const int sd = 2*wz0 + ((p>>2)&1);
          const int sh = 2*wy0 + ((p>>1)&1);
          const int sw = 2*wx0 + (p&1);
          cnts[p] = (sd >= 62 ? sd - 61 : 0)*9 + (sh >= 62 ? sh - 61 : 0)*3
                  + (sw >= 62 ? sw - 61 : 0);
        }
#pragma unroll
        for (int kk = 0; kk < 8; ++kk)
          if (cnts[kk] != cnts[cg]) sc8[kk] -= 100.f;
      }
      float mx = sc8[0];
#pragma unroll
      for (int kk = 1; kk < 8; ++kk) mx = fmaxf(mx, sc8[kk]);
      float pr[8], lsum = 0.f;
#pragma unroll
      for (int kk = 0; kk < 8; ++kk) { pr[kk] = __expf(sc8[kk] - mx); lsum += pr[kk]; }
      const float inv = __builtin_amdgcn_rcpf(lsum);
      float o[8];
#pragma unroll
      for (int d = 0; d < 8; ++d) o[d] = 0.f;
#pragma unroll
      for (int kk = 0; kk < 8; ++kk) {
        const f32x4 va = *(const f32x4*)&vF[(w*8 + kk)*68 + s8*8];
        const f32x4 vc = *(const f32x4*)&vF[(w*8 + kk)*68 + s8*8 + 4];
        o[0] += pr[kk]*va[0]; o[1] += pr[kk]*va[1];
        o[2] += pr[kk]*va[2]; o[3] += pr[kk]*va[3];
        o[4] += pr[kk]*vc[0]; o[5] += pr[kk]*vc[1];
        o[6] += pr[kk]*vc[2]; o[7] += pr[kk]*vc[3];
      }
      short8 ov;
#pragma unroll
      for (int d = 0; d < 8; ++d) ov[d] = (short)f2bf(o[d] * inv);
      *(short8*)&aL[tq*72 + s8*8] = ov;    // O -> aL (dead since B2-fenced P2)
    }
    // prefetch residual x + scatter offsets (x is L3/L2-resident)
    int offs[8]; float xr[8];
#pragma unroll
    for (int mt = 0; mt < 2; ++mt)
#pragma unroll
      for (int r = 0; r < 4; ++r) {
        const int off = scat(chunk, mt*16 + quad*4 + r) + w*16 + col;
        offs[mt*4 + r] = off;
        xr[mt*4 + r]   = ld<F32>(x, off);
      }
    __syncthreads();                                       // B3: O ready

    // ---- phase 4: proj MFMA (A = O from aL) + scattered residual write ----
    {
      f32x4 c0 = (f32x4){0.f,0.f,0.f,0.f}, c1 = (f32x4){0.f,0.f,0.f,0.f};
      c0 = MFMA(*(const short8*)&aL[(col)*72 + quad*8],         bp[0], c0, 0, 0, 0);
      c0 = MFMA(*(const short8*)&aL[(col)*72 + 32 + quad*8],    bp[1], c0, 0, 0, 0);
      c1 = MFMA(*(const short8*)&aL[(16+col)*72 + quad*8],      bp[0], c1, 0, 0, 0);
      c1 = MFMA(*(const short8*)&aL[(16+col)*72 + 32 + quad*8], bp[1], c1, 0, 0, 0);
#pragma unroll
      for (int r = 0; r < 4; ++r) {
        out[offs[r]]     = xr[r]     + c0[r] + pbv;
        out[offs[4 + r]] = xr[4 + r] + c1[r] + pbv;
      }
    }
    __syncthreads();   // B4: fence aL reads vs next chunk's phase-1 writes
  }
}

__global__ __launch_bounds__(256, 4)
void attn_kernel(const void* __restrict__ x,
                 const void* __restrict__ n1g, const void* __restrict__ n1b,
                 const void* __restrict__ qkvw, const void* __restrict__ qkvb,
                 const void* __restrict__ rpb,
                 const void* __restrict__ projw, const void* __restrict__ projb,
                 const int* __restrict__ flag, float* __restrict__ out)
{
  __shared__ __align__(16) u16   aL[32*72];   // 4.6 KB  LN1 out, then O (bf16)
  __shared__ __align__(16) float qF[32*68];   // 8.7 KB  q (f32)
  __shared__ __align__(16) float kF[32*68];   // 8.7 KB  k (f32)
  __shared__ __align__(16) float vF[32*68];   // 8.7 KB  v (f32)  (30.7 KB)
  if (*flag)
    attn_body<true >(x, n1g, n1b, qkvw, qkvb, rpb, projw, projb, out, aL, qF, kF, vF);
  else
    attn_body<false>(x, n1g, n1b, qkvw, qkvb, rpb, projw, projb, out, aL, qF, kF, vF);
}

// ---------------------------------------------------------------------------
// Kernel 2: LN2 + MLP(64->256 GELU ->64) + residual, in-place on out (=y).
// Token-major group-reduce LN2; y stashed in LDS (yL) and reused as residual
// (removes the second global read of io per chunk). Cross-chunk prefetch.
// Byte-identical to the verified round-4 version.
// ---------------------------------------------------------------------------
template<bool F32>
__device__ __forceinline__ void mlp_body(
    float* __restrict__ io,
    const void* __restrict__ n2g, const void* __restrict__ n2b,
    const void* __restrict__ mw1, const void* __restrict__ mb1,
    const void* __restrict__ mw2, const void* __restrict__ mb2,
    u16* __restrict__ aL, u16* __restrict__ hL, float* __restrict__ yL)
{
  const int tid  = threadIdx.x;
  const int w    = tid >> 6, l = tid & 63;
  const int quad = l >> 4,  col = l & 15;
  const int s8   = l >> 3,  cg  = l & 7;
  const int ltok = w*8 + s8;

  float g2v[8], be2v[8];
#pragma unroll
  for (int j = 0; j < 8; ++j) {
    g2v[j]  = ld<F32>(n2g, cg*8 + j);
    be2v[j] = ld<F32>(n2b, cg*8 + j);
  }

  short8 b1f[2][4];                  // [kt][nt], W1 cols w*64+nt*16+col
#pragma unroll
  for (int kt = 0; kt < 2; ++kt)
#pragma unroll
    for (int nt = 0; nt < 4; ++nt) {
      short8 f;
#pragma unroll
      for (int j = 0; j < 8; ++j)
        f[j] = (short)f2bf(ld<F32>(mw1, (kt*32 + quad*8 + j)*256 + w*64 + nt*16 + col));
      b1f[kt][nt] = f;
    }
  short8 b2f[8];                     // [kt], W2 col w*16+col
#pragma unroll
  for (int kt = 0; kt < 8; ++kt) {
    short8 f;
#pragma unroll
    for (int j = 0; j < 8; ++j)
      f[j] = (short)f2bf(ld<F32>(mw2, (kt*32 + quad*8 + j)*64 + w*16 + col));
    b2f[kt] = f;
  }
  float b1vv[4];
#pragma unroll
  for (int nt = 0; nt < 4; ++nt) b1vv[nt] = ld<F32>(mb1, w*64 + nt*16 + col);
  const float b2vv = ld<F32>(mb2, w*16 + col);

  float pf[8];
  {
    const float* p = &io[(blockIdx.x*32 + ltok)*64 + cg*8];
    const f32x4 a = *(const f32x4*)p;
    const f32x4 c = *(const f32x4*)(p + 4);
    pf[0]=a[0]; pf[1]=a[1]; pf[2]=a[2]; pf[3]=a[3];
    pf[4]=c[0]; pf[5]=c[1]; pf[6]=c[2]; pf[7]=c[3];
  }

  for (int chunk = blockIdx.x; chunk < 16384; chunk += 2048) {
    // ---- LN2 (token-major group reduce) + stash y in yL ----
    {
      float s1 = 0.f, sq = 0.f;
#pragma unroll
      for (int j = 0; j < 8; ++j) { s1 += pf[j]; sq += pf[j]*pf[j]; }
#pragma unroll
      for (int m = 1; m < 8; m <<= 1) {
        s1 += __shfl_xor(s1, m);
        sq += __shfl_xor(sq, m);
      }
      const float mu  = s1 * 0.015625f;
      const float var = sq * 0.015625f - mu * mu;
      const float rs  = rsqrtf(var + 1e-5f);
      short8 av;
#pragma unroll
      for (int j = 0; j < 8; ++j)
        av[j] = (short)f2bf((pf[j] - mu) * rs * g2v[j] + be2v[j]);
      *(short8*)&aL[ltok*72 + cg*8] = av;
      *(f32x4*)&yL[ltok*68 + cg*8]     = (f32x4){pf[0], pf[1], pf[2], pf[3]};
      *(f32x4*)&yL[ltok*68 + cg*8 + 4] = (f32x4){pf[4], pf[5], pf[6], pf[7]};
    }
    if (chunk + 2048 < 16384) {
      const float* p = &io[((chunk + 2048)*32 + ltok)*64 + cg*8];
      const f32x4 a = *(const f32x4*)p;
      const f32x4 c = *(const f32x4*)(p + 4);
      pf[0]=a[0]; pf[1]=a[1]; pf[2]=a[2]; pf[3]=a[3];
      pf[4]=c[0]; pf[5]=c[1]; pf[6]=c[2]; pf[7]=c[3];
    }
    __syncthreads();                                       // B1: aL/yL ready

    // ---- phase 1: 32x64 @ 64x256 -> wave's 32x64 slab, GELU -> hL ----
    {
      short8 aF[2][2];
#pragma unroll
      for (int mt = 0; mt < 2; ++mt)
#pragma unroll
        for (int kt = 0; kt < 2; ++kt)
          aF[mt][kt] = *(const short8*)&aL[(mt*16 + col)*72 + kt*32 + quad*8];
#pragma unroll
      for (int nt = 0; nt < 4; ++nt) {
        f32x4 m0 = (f32x4){0.f,0.f,0.f,0.f}, m1 = (f32x4){0.f,0.f,0.f,0.f};
        m0 = MFMA(aF[0][0], b1f[0][nt], m0, 0, 0, 0);
        m0 = MFMA(aF[0][1], b1f[1][nt], m0, 0, 0, 0);
        m1 = MFMA(aF[1][0], b1f[0][nt], m1, 0, 0, 0);
        m1 = MFMA(aF[1][1], b1f[1][nt], m1, 0, 0, 0);
        const float bb = b1vv[nt];
#pragma unroll
        for (int r = 0; r < 4; ++r) {
          {
            const float h = m0[r] + bb;
            const float u = h * (1.5957691216f + 0.0713548162f * (h * h));
            const float e = __expf(u);
            hL[(quad*4 + r)*264 + w*64 + nt*16 + col] =
                f2bf(h - h * __builtin_amdgcn_rcpf(e + 1.f));
          }
          {
            const float h = m1[r] + bb;
            const float u = h * (1.5957691216f + 0.0713548162f * (h * h));
            const float e = __expf(u);
            hL[(16 + quad*4 + r)*264 + w*64 + nt*16 + col] =
                f2bf(h - h * __builtin_amdgcn_rcpf(e + 1.f));
          }
        }
      }
    }
    __syncthreads();                                       // B2: hL ready

    // ---- phase 2: 32x256 @ 256x64 + residual from yL -> out ----
    {
      f32x4 o0 = (f32x4){0.f,0.f,0.f,0.f}, o1 = (f32x4){0.f,0.f,0.f,0.f};
#pragma unroll
      for (int kt = 0; kt < 8; ++kt) {
        o0 = MFMA(*(const short8*)&hL[(col)*264 + kt*32 + quad*8],    b2f[kt], o0, 0, 0, 0);
        o1 = MFMA(*(const short8*)&hL[(16+col)*264 + kt*32 + quad*8], b2f[kt], o1, 0, 0, 0);
      }
#pragma unroll
      for (int r = 0; r < 4; ++r) {
        const int r0 = quad*4 + r, r1 = 16 + quad*4 + r;
        io[(chunk*32 + r0)*64 + w*16 + col] = yL[r0*68 + w*16 + col] + o0[r] + b2vv;
        io[(chunk*32 + r1)*64 + w*16 + col] = yL[r1*68 + w*16 + col] + o1[r] + b2vv;
      }
    }
    __syncthreads();   // B3: fence yL/hL reads vs next chunk's writes
  }
}

__global__ __launch_bounds__(256, 4)
void mlp_kernel(float* __restrict__ io,
                const void* __restrict__ n2g, const void* __restrict__ n2b,
                const void* __restrict__ mw1, const void* __restrict__ mb1,
                const void* __restrict__ mw2, const void* __restrict__ mb2,
                const int* __restrict__ flag)
{
  __shared__ __align__(16) u16   aL[32 * 72];    //  4.6 KB
  __shared__ __align__(16) u16   hL[32 * 264];   // 16.9 KB
  __shared__ __align__(16) float yL[32 * 68];    //  8.7 KB  (30.2 KB total)
  if (*flag)
    mlp_body<true >(io, n2g, n2b, mw1, mb1, mw2, mb2, aL, hL, yL);
  else
    mlp_body<false>(io, n2g, n2b, mw1, mb1, mw2, mb2, aL, hL, yL);
}

extern "C" void kernel_launch(void* const* d_in, const int* in_sizes, int n_in,
                              void* d_out, int out_size, void* d_ws, size_t ws_size,
                              hipStream_t stream) {
  const void* x     = d_in[0];
  const void* n1g   = d_in[1];
  const void* n1b   = d_in[2];
  const void* qkvw  = d_in[3];
  const void* qkvb  = d_in[4];
  const void* rpb   = d_in[5];
  const void* projw = d_in[6];
  const void* projb = d_in[7];
  const void* n2g   = d_in[8];
  const void* n2b   = d_in[9];
  const void* mw1   = d_in[10];
  const void* mb1   = d_in[11];
  const void* mw2   = d_in[12];
  const void* mb2   = d_in[13];
  float* out = (float*)d_out;
  int* flag  = (int*)d_ws;

  detect_kernel<<<dim3(1), dim3(64), 0, stream>>>(x, flag);
  attn_kernel<<<dim3(2048), dim3(256), 0, stream>>>(
      x, n1g, n1b, qkvw, qkvb, rpb, projw, projb, flag, out);
  mlp_kernel<<<dim3(2048), dim3(256), 0, stream>>>(
      out, n2g, n2b, mw1, mb1, mw2, mb2, flag);
}